// Round 11
// baseline (256.254 us; speedup 1.0000x reference)
//
#include <hip/hip_runtime.h>

#define N 8192
#define D 512

typedef __attribute__((ext_vector_type(8))) short short8;
typedef __attribute__((ext_vector_type(4))) float f32x4;

typedef const __attribute__((address_space(1))) unsigned int* gas_t;
typedef __attribute__((address_space(3))) unsigned int* las_t;

static __device__ __forceinline__ unsigned short f2bf(float f) {
    unsigned u = __float_as_uint(f);
    unsigned r = (u + 0x7FFFu + ((u >> 16) & 1u)) >> 16;
    return (unsigned short)r;
}
static __device__ __forceinline__ float bf2f(unsigned u) {
    return __uint_as_float(u << 16);
}
static __device__ __forceinline__ void gl_lds16(const unsigned short* g, char* l) {
    __builtin_amdgcn_global_load_lds((gas_t)g, (las_t)l, 16, 0, 0);
}
// triangle cumulative for the 128x128 grid of 64-wide tiles: row r owns (128-r) tiles
static __device__ __forceinline__ int tc128(int r) { return r * (257 - r) / 2; }

// K0: pack thetas -> float4 (x,y,z,|t|^2); init per-row accumulators + d2max.
__global__ void kpack(const float* __restrict__ th, float4* __restrict__ th4,
                      float* __restrict__ srow, unsigned* __restrict__ jminrow,
                      unsigned* __restrict__ negrow, unsigned* __restrict__ d2mb) {
    int i = blockIdx.x * 256 + threadIdx.x;
    if (i < N) {
        float x = th[3 * i], y = th[3 * i + 1], z = th[3 * i + 2];
        float4 v; v.x = x; v.y = y; v.z = z; v.w = x * x + y * y + z * z;
        th4[i] = v;
        srow[i] = 0.0f;
        jminrow[i] = 0xFFFFFFFFu;
        negrow[i] = 0u;
    }
    if (i == 0) *d2mb = 0u;
}

// K1: row-normalize embeddings -> bf16 e[N][D], PRE-SCALED by sqrt(10*log2(e)).
// Blocks 0..255 additionally compute the global theta-d2max (th4 ready via kpack).
__global__ void knorm(const float* __restrict__ emb, unsigned short* __restrict__ e,
                      const float4* __restrict__ th4, unsigned* __restrict__ d2mb) {
    int w    = threadIdx.x >> 6;
    int row  = blockIdx.x * 4 + w;
    int lane = threadIdx.x & 63;
    const float4* src = (const float4*)(emb + (size_t)row * D);
    float4 v0 = src[lane * 2];
    float4 v1 = src[lane * 2 + 1];
    float ss = v0.x*v0.x + v0.y*v0.y + v0.z*v0.z + v0.w*v0.w
             + v1.x*v1.x + v1.y*v1.y + v1.z*v1.z + v1.w*v1.w;
#pragma unroll
    for (int off = 1; off < 64; off <<= 1) ss += __shfl_xor(ss, off, 64);
    // 3.7982826^2 = 14.42695 = 10*log2(e): acc becomes exp2 argument directly
    float inv = 3.7982826f / fmaxf(sqrtf(ss), 1e-12f);
    unsigned short h0 = f2bf(v0.x * inv), h1 = f2bf(v0.y * inv);
    unsigned short h2 = f2bf(v0.z * inv), h3 = f2bf(v0.w * inv);
    unsigned short h4 = f2bf(v1.x * inv), h5 = f2bf(v1.y * inv);
    unsigned short h6 = f2bf(v1.z * inv), h7 = f2bf(v1.w * inv);
    uint4 pk;
    pk.x = (unsigned)h0 | ((unsigned)h1 << 16);
    pk.y = (unsigned)h2 | ((unsigned)h3 << 16);
    pk.z = (unsigned)h4 | ((unsigned)h5 << 16);
    pk.w = (unsigned)h6 | ((unsigned)h7 << 16);
    ((uint4*)(e + (size_t)row * D))[lane] = pk;

    if (blockIdx.x < 256) {
        int widx = blockIdx.x * 4 + w;
        int q0 = widx * 4;
        int m0 = N - 4 - q0;
        float4 a0 = th4[q0], a1 = th4[q0 + 1], a2 = th4[q0 + 2], a3 = th4[q0 + 3];
        float4 b0 = th4[m0], b1 = th4[m0 + 1], b2 = th4[m0 + 2], b3 = th4[m0 + 3];
        float m = 0.0f;
        for (int j = q0 + 1 + lane; j < N; j += 64) {
            float4 tj = th4[j];
            float d;
            d = a0.w + tj.w - 2.0f * (a0.x*tj.x + a0.y*tj.y + a0.z*tj.z); m = fmaxf(m, d);
            d = a1.w + tj.w - 2.0f * (a1.x*tj.x + a1.y*tj.y + a1.z*tj.z); m = fmaxf(m, d);
            d = a2.w + tj.w - 2.0f * (a2.x*tj.x + a2.y*tj.y + a2.z*tj.z); m = fmaxf(m, d);
            d = a3.w + tj.w - 2.0f * (a3.x*tj.x + a3.y*tj.y + a3.z*tj.z); m = fmaxf(m, d);
        }
        for (int j = m0 + 1 + lane; j < N; j += 64) {
            float4 tj = th4[j];
            float d;
            d = b0.w + tj.w - 2.0f * (b0.x*tj.x + b0.y*tj.y + b0.z*tj.z); m = fmaxf(m, d);
            d = b1.w + tj.w - 2.0f * (b1.x*tj.x + b1.y*tj.y + b1.z*tj.z); m = fmaxf(m, d);
            d = b2.w + tj.w - 2.0f * (b2.x*tj.x + b2.y*tj.y + b2.z*tj.z); m = fmaxf(m, d);
            d = b3.w + tj.w - 2.0f * (b3.x*tj.x + b3.y*tj.y + b3.z*tj.z); m = fmaxf(m, d);
        }
#pragma unroll
        for (int off = 1; off < 64; off <<= 1) m = fmaxf(m, __shfl_xor(m, off, 64));
        if (lane == 0) atomicMax(d2mb, __float_as_uint(m));
    }
}

// K4: symmetric fused GEMM, 64x64 tile per SINGLE-WAVE block over the 128x128
// upper-triangle grid (8256 blocks = 8 XCD x 1032). Zero barriers: each wave runs
// a private pipeline {STAGE(t+1) -> counted vmcnt(16) -> compute(t)} on a 32 KB
// double-buffered LDS (r4's proven swizzle geometry) -> 5 independent blocks/CU.
// acc[4][4] = 64 AGPR. Epilogue: ballot masks + shuffle sums + direct atomics.
__global__ __launch_bounds__(64) void kmain(
    const unsigned short* __restrict__ e, const float4* __restrict__ th4,
    const unsigned* __restrict__ d2mb, float* __restrict__ srow,
    unsigned* __restrict__ jminrow, unsigned* __restrict__ negrow) {
    __shared__ __align__(16) char smem[32768];   // 2 bufs x (A 8K + B 8K)

    const int lane = threadIdx.x;     // 0..63, one wave
    const int fr   = lane & 15;
    const int fq   = lane >> 4;

    // XCD-aware bijective swizzle: 8256 = 8 x 1032; triangle decode on 128 rows
    const int bid = (int)blockIdx.x;
    const int swz = (bid & 7) * 1032 + (bid >> 3);
    int rb = (int)((257.0f - sqrtf(66049.0f - 8.0f * (float)swz)) * 0.5f);
    rb = rb < 0 ? 0 : (rb > 127 ? 127 : rb);
    while (tc128(rb + 1) <= swz) rb++;
    while (tc128(rb) > swz) rb--;
    const int cb = rb + (swz - tc128(rb));
    const bool isdiag = (rb == cb);
    const int r0 = rb * 64, c0 = cb * 64;

    // staging geometry (r4 verbatim, 8 chunks of 8 rows x 128 B per matrix):
    // lane l covers row l>>3 of each chunk, 16B-slot l&7; LDS dest linear
    // chunk*1024 + lane*16; global source slot pre-swizzled so that
    // LDS[row][s] = global(row, s ^ (row&7)).
    const int l8 = lane >> 3, l7 = lane & 7;
    const int srcoff = ((l7 ^ l8) << 3);   // elements within the 64-elem K-slab
    const unsigned short* pA0 = e + (size_t)(r0 + l8) * D + srcoff;
    const unsigned short* pB0 = e + (size_t)(c0 + l8) * D + srcoff;

    f32x4 acc[4][4];
#pragma unroll
    for (int mt = 0; mt < 4; mt++)
#pragma unroll
        for (int nt = 0; nt < 4; nt++) acc[mt][nt] = (f32x4){0.f, 0.f, 0.f, 0.f};

#define STAGE(T, BUF) { \
    const int k0_ = (T) * 64; char* d_ = smem + (BUF) * 16384;             \
    _Pragma("unroll")                                                      \
    for (int cc = 0; cc < 8; cc++)                                         \
        gl_lds16(pA0 + cc * 8 * D + k0_, d_ + cc * 1024 + lane * 16);      \
    _Pragma("unroll")                                                      \
    for (int cc = 0; cc < 8; cc++)                                         \
        gl_lds16(pB0 + cc * 8 * D + k0_, d_ + 8192 + cc * 1024 + lane * 16); }

#define COMPUTE(BUF) { \
    const char* cA_ = smem + (BUF) * 16384;                                \
    const char* cB_ = cA_ + 8192;                                          \
    _Pragma("unroll")                                                      \
    for (int ks = 0; ks < 2; ++ks) {                                       \
        const int kb = ((ks << 6) | (fq << 4)) ^ ((fr & 7) << 4);          \
        short8 a_[4], b_[4];                                               \
        _Pragma("unroll")                                                  \
        for (int mt = 0; mt < 4; mt++)                                     \
            a_[mt] = *(const short8*)(cA_ + (mt * 16 + fr) * 128 + kb);    \
        _Pragma("unroll")                                                  \
        for (int nt = 0; nt < 4; nt++)                                     \
            b_[nt] = *(const short8*)(cB_ + (nt * 16 + fr) * 128 + kb);    \
        _Pragma("unroll")                                                  \
        for (int mt = 0; mt < 4; mt++)                                     \
        _Pragma("unroll")                                                  \
        for (int nt = 0; nt < 4; nt++)                                     \
            acc[mt][nt] = __builtin_amdgcn_mfma_f32_16x16x32_bf16(         \
                a_[mt], b_[nt], acc[mt][nt], 0, 0, 0);                     \
    } }

// wave-private pipeline step: issue next tile's 16 loads, then counted wait
// (drains tile T's loads, leaves T+1's in flight), then compute. NO barriers.
#define KST(T)                                                             \
    if ((T) + 1 < 8) { STAGE((T) + 1, ((T) + 1) & 1) }                     \
    if ((T) + 1 < 8) { asm volatile("s_waitcnt vmcnt(16)" ::: "memory"); } \
    else             { asm volatile("s_waitcnt vmcnt(0)"  ::: "memory"); } \
    __builtin_amdgcn_sched_barrier(0);                                     \
    COMPUTE((T) & 1)

    STAGE(0, 0)
    KST(0) KST(1) KST(2) KST(3) KST(4) KST(5) KST(6) KST(7)
#undef KST
#undef COMPUTE
#undef STAGE

    // ---- fused epilogue (acc is the exp2 argument directly; no LDS, no barriers) ----
    const float dmax = sqrtf(__uint_as_float(*d2mb)) + 1e-8f;
    const float p2 = 0.0225f * dmax * dmax;
    const float n2 = 0.1225f * dmax * dmax;

    float4 thj[4];
#pragma unroll
    for (int nt = 0; nt < 4; nt++) thj[nt] = th4[c0 + nt * 16 + fr];

    float    csum[4]; unsigned cjm[4], cng[4];
#pragma unroll
    for (int nt = 0; nt < 4; nt++) { csum[nt] = 0.0f; cjm[nt] = 0xFFFFFFFFu; cng[nt] = 0u; }

#pragma unroll
    for (int mt = 0; mt < 4; mt++) {
#pragma unroll
        for (int rr = 0; rr < 4; rr++) {
            const int i = r0 + mt * 16 + fq * 4 + rr;
            const float4 ti = th4[i];
            float sv = 0.0f; unsigned jv = 0xFFFFFFFFu; unsigned nv = 0u;
#pragma unroll
            for (int nt = 0; nt < 4; nt++) {
                const int j = c0 + nt * 16 + fr;
                const float4 tj = thj[nt];
                float dot = ti.x * tj.x + ti.y * tj.y + ti.z * tj.z;
                float d2 = fmaf(-2.0f, dot, ti.w + tj.w);
                bool pos = isdiag ? ((d2 < p2) && (j != i)) : (d2 < p2);
                bool neg = (d2 > n2);
                float c = (pos || neg) ? exp2f(acc[mt][nt][rr]) : 0.0f;
                sv += c;
                unsigned long long bp = __ballot(pos);
                unsigned long long bn = __ballot(neg);
                // row-side: my fq group's 16 column bits
                unsigned fp = (unsigned)((bp >> (fq << 4)) & 0xFFFFull);
                unsigned fn = (unsigned)((bn >> (fq << 4)) & 0xFFFFull);
                if (fp) jv = min(jv, (unsigned)(c0 + nt * 16 + __builtin_ctz(fp)));
                nv |= (fn != 0u) ? 1u : 0u;
                if (!isdiag) {
                    csum[nt] += c;
                    // col-side: my fr column's bits at fq = 0..3
                    unsigned long long m4p = (bp >> fr) & 0x0001000100010001ull;
                    unsigned long long m4n = (bn >> fr) & 0x0001000100010001ull;
                    if (m4p) {
                        int fqs = __builtin_ctzll(m4p) >> 4;
                        cjm[nt] = min(cjm[nt], (unsigned)(r0 + mt * 16 + rr + 4 * fqs));
                    }
                    cng[nt] |= (m4n != 0ull) ? 1u : 0u;
                }
            }
            // row-side float reduce over the 16 fr-lanes, then direct atomics
#pragma unroll
            for (int off = 1; off < 16; off <<= 1) sv += __shfl_xor(sv, off, 64);
            if (fr == 0) {
                atomicAdd(&srow[i], sv);
                atomicMin(&jminrow[i], jv);
                atomicOr(&negrow[i], nv);
            }
        }
    }

    if (!isdiag) {
#pragma unroll
        for (int nt = 0; nt < 4; nt++) {
            float sv = csum[nt];
            sv += __shfl_xor(sv, 16, 64);
            sv += __shfl_xor(sv, 32, 64);
            if (fq == 0) {
                const int j = c0 + nt * 16 + fr;
                atomicAdd(&srow[j], sv);
                atomicMin(&jminrow[j], cjm[nt]);
                atomicOr(&negrow[j], cng[nt]);
            }
        }
    }
}

// K5: per-row finalize. e is pre-scaled: sim = dot_scaled * ln2.
__global__ void krow(const unsigned short* __restrict__ e, const float* __restrict__ srow,
                     const unsigned* __restrict__ jminrow, const unsigned* __restrict__ negrow,
                     float* __restrict__ pr, float* __restrict__ vf) {
    int row  = blockIdx.x * 4 + (threadIdx.x >> 6);
    int lane = threadIdx.x & 63;
    unsigned jmv = jminrow[row];
    bool valid = (jmv != 0xFFFFFFFFu) && (negrow[row] != 0u);
    float p = 0.0f;
    if (valid) {
        const uint4* a = (const uint4*)(e + (size_t)row * D);
        const uint4* b = (const uint4*)(e + (size_t)jmv * D);
        uint4 va = a[lane], vb = b[lane];
        float dot = 0.0f;
        dot += bf2f(va.x & 0xFFFFu) * bf2f(vb.x & 0xFFFFu);
        dot += bf2f(va.x >> 16)     * bf2f(vb.x >> 16);
        dot += bf2f(va.y & 0xFFFFu) * bf2f(vb.y & 0xFFFFu);
        dot += bf2f(va.y >> 16)     * bf2f(vb.y >> 16);
        dot += bf2f(va.z & 0xFFFFu) * bf2f(vb.z & 0xFFFFu);
        dot += bf2f(va.z >> 16)     * bf2f(vb.z >> 16);
        dot += bf2f(va.w & 0xFFFFu) * bf2f(vb.w & 0xFFFFu);
        dot += bf2f(va.w >> 16)     * bf2f(vb.w >> 16);
#pragma unroll
        for (int off = 1; off < 64; off <<= 1) dot += __shfl_xor(dot, off, 64);
        p = logf(srow[row]) - dot * 0.69314718f;
    }
    if (lane == 0) { pr[row] = p; vf[row] = valid ? 1.0f : 0.0f; }
}

// K6: deterministic fixed-tree reduction -> scalar loss.
__global__ void kfinal(const float* __restrict__ pr, const float* __restrict__ vf,
                       float* __restrict__ out) {
    __shared__ float ls[1024];
    __shared__ float lc[1024];
    int t = threadIdx.x;
    float sv = 0.0f, cv = 0.0f;
#pragma unroll
    for (int k = 0; k < 8; k++) { sv += pr[t * 8 + k]; cv += vf[t * 8 + k]; }
    ls[t] = sv; lc[t] = cv;
    __syncthreads();
    for (int off = 512; off > 0; off >>= 1) {
        if (t < off) { ls[t] += ls[t + off]; lc[t] += lc[t + off]; }
        __syncthreads();
    }
    if (t == 0) out[0] = (lc[0] > 0.0f) ? (ls[0] / lc[0]) : 0.0f;
}

extern "C" void kernel_launch(void* const* d_in, const int* in_sizes, int n_in,
                              void* d_out, int out_size, void* d_ws, size_t ws_size,
                              hipStream_t stream) {
    const float* emb = (const float*)d_in[0];
    const float* th  = (const float*)d_in[1];
    float* out = (float*)d_out;
    char* ws = (char*)d_ws;

    unsigned short* e    = (unsigned short*)(ws);
    float4*   th4        = (float4*)(ws + 8388608);
    float*    srow       = (float*)(ws + 8519680);
    unsigned* jminr      = (unsigned*)(ws + 8552448);
    unsigned* negr       = (unsigned*)(ws + 8585216);
    float*    pr         = (float*)(ws + 8617984);
    float*    vf         = (float*)(ws + 8650752);
    unsigned* d2mb       = (unsigned*)(ws + 8683520);

    kpack<<<32, 256, 0, stream>>>(th, th4, srow, jminr, negr, d2mb);
    knorm<<<N / 4, 256, 0, stream>>>(emb, e, th4, d2mb);
    kmain<<<8256, 64, 0, stream>>>(e, th4, d2mb, srow, jminr, negr);
    krow<<<N / 4, 256, 0, stream>>>(e, srow, jminr, negr, pr, vf);
    kfinal<<<1, 1024, 0, stream>>>(pr, vf, out);
}

// Round 12
// 126.692 us; speedup vs baseline: 2.0227x; 2.0227x over previous
//
#include <hip/hip_runtime.h>

#define N 8192
#define D 512

typedef __attribute__((ext_vector_type(8))) short short8;
typedef __attribute__((ext_vector_type(4))) float f32x4;

typedef const __attribute__((address_space(1))) unsigned int* gas_t;
typedef __attribute__((address_space(3))) unsigned int* las_t;

static __device__ __forceinline__ unsigned short f2bf(float f) {
    unsigned u = __float_as_uint(f);
    unsigned r = (u + 0x7FFFu + ((u >> 16) & 1u)) >> 16;
    return (unsigned short)r;
}
static __device__ __forceinline__ float bf2f(unsigned u) {
    return __uint_as_float(u << 16);
}
static __device__ __forceinline__ void gl_lds16(const unsigned short* g, char* l) {
    __builtin_amdgcn_global_load_lds((gas_t)g, (las_t)l, 16, 0, 0);
}
// triangle cumulative for the 64x64 grid of 128-wide tiles: row r owns (64-r) tiles
static __device__ __forceinline__ int tri_cum(int r) { return r * (129 - r) / 2; }

// K0: pack thetas -> float4 (x,y,z,|t|^2); init per-row accumulators + d2max.
__global__ void kpack(const float* __restrict__ th, float4* __restrict__ th4,
                      float* __restrict__ srow, unsigned* __restrict__ jminrow,
                      unsigned* __restrict__ negrow, unsigned* __restrict__ d2mb) {
    int i = blockIdx.x * 256 + threadIdx.x;
    if (i < N) {
        float x = th[3 * i], y = th[3 * i + 1], z = th[3 * i + 2];
        float4 v; v.x = x; v.y = y; v.z = z; v.w = x * x + y * y + z * z;
        th4[i] = v;
        srow[i] = 0.0f;
        jminrow[i] = 0xFFFFFFFFu;
        negrow[i] = 0u;
    }
    if (i == 0) *d2mb = 0u;
}

// K1: row-normalize embeddings -> bf16 e[N][D], PRE-SCALED by sqrt(10*log2(e)).
// Blocks 0..255 additionally compute the global theta-d2max (th4 ready via kpack).
__global__ void knorm(const float* __restrict__ emb, unsigned short* __restrict__ e,
                      const float4* __restrict__ th4, unsigned* __restrict__ d2mb) {
    int w    = threadIdx.x >> 6;
    int row  = blockIdx.x * 4 + w;
    int lane = threadIdx.x & 63;
    const float4* src = (const float4*)(emb + (size_t)row * D);
    float4 v0 = src[lane * 2];
    float4 v1 = src[lane * 2 + 1];
    float ss = v0.x*v0.x + v0.y*v0.y + v0.z*v0.z + v0.w*v0.w
             + v1.x*v1.x + v1.y*v1.y + v1.z*v1.z + v1.w*v1.w;
#pragma unroll
    for (int off = 1; off < 64; off <<= 1) ss += __shfl_xor(ss, off, 64);
    // 3.7982826^2 = 14.42695 = 10*log2(e): acc becomes exp2 argument directly
    float inv = 3.7982826f / fmaxf(sqrtf(ss), 1e-12f);
    unsigned short h0 = f2bf(v0.x * inv), h1 = f2bf(v0.y * inv);
    unsigned short h2 = f2bf(v0.z * inv), h3 = f2bf(v0.w * inv);
    unsigned short h4 = f2bf(v1.x * inv), h5 = f2bf(v1.y * inv);
    unsigned short h6 = f2bf(v1.z * inv), h7 = f2bf(v1.w * inv);
    uint4 pk;
    pk.x = (unsigned)h0 | ((unsigned)h1 << 16);
    pk.y = (unsigned)h2 | ((unsigned)h3 << 16);
    pk.z = (unsigned)h4 | ((unsigned)h5 << 16);
    pk.w = (unsigned)h6 | ((unsigned)h7 << 16);
    ((uint4*)(e + (size_t)row * D))[lane] = pk;

    if (blockIdx.x < 256) {
        int widx = blockIdx.x * 4 + w;
        int q0 = widx * 4;
        int m0 = N - 4 - q0;
        float4 a0 = th4[q0], a1 = th4[q0 + 1], a2 = th4[q0 + 2], a3 = th4[q0 + 3];
        float4 b0 = th4[m0], b1 = th4[m0 + 1], b2 = th4[m0 + 2], b3 = th4[m0 + 3];
        float m = 0.0f;
        for (int j = q0 + 1 + lane; j < N; j += 64) {
            float4 tj = th4[j];
            float d;
            d = a0.w + tj.w - 2.0f * (a0.x*tj.x + a0.y*tj.y + a0.z*tj.z); m = fmaxf(m, d);
            d = a1.w + tj.w - 2.0f * (a1.x*tj.x + a1.y*tj.y + a1.z*tj.z); m = fmaxf(m, d);
            d = a2.w + tj.w - 2.0f * (a2.x*tj.x + a2.y*tj.y + a2.z*tj.z); m = fmaxf(m, d);
            d = a3.w + tj.w - 2.0f * (a3.x*tj.x + a3.y*tj.y + a3.z*tj.z); m = fmaxf(m, d);
        }
        for (int j = m0 + 1 + lane; j < N; j += 64) {
            float4 tj = th4[j];
            float d;
            d = b0.w + tj.w - 2.0f * (b0.x*tj.x + b0.y*tj.y + b0.z*tj.z); m = fmaxf(m, d);
            d = b1.w + tj.w - 2.0f * (b1.x*tj.x + b1.y*tj.y + b1.z*tj.z); m = fmaxf(m, d);
            d = b2.w + tj.w - 2.0f * (b2.x*tj.x + b2.y*tj.y + b2.z*tj.z); m = fmaxf(m, d);
            d = b3.w + tj.w - 2.0f * (b3.x*tj.x + b3.y*tj.y + b3.z*tj.z); m = fmaxf(m, d);
        }
#pragma unroll
        for (int off = 1; off < 64; off <<= 1) m = fmaxf(m, __shfl_xor(m, off, 64));
        if (lane == 0) atomicMax(d2mb, __float_as_uint(m));
    }
}

// K4: symmetric fused GEMM, 128x128 tile over the 64x64 triangle grid (2080 blocks),
// 256 threads = 4 waves (2Mx2N, 64x64/wave, acc 4x4). BK=32, double-buffered LDS
// now only 32 KB -> ~4 co-resident blocks/CU (16 waves): the m97/m114 regime where
// co-resident blocks in different phases fill each other's barrier drains and
// overlap the epilogue VALU with other blocks' MFMA. Same 2-phase loop as r4
// (best measured), same proven swizzle (r7's BK=32 variant), same epilogue.
__global__ __launch_bounds__(256) void kmain(
    const unsigned short* __restrict__ e, const float4* __restrict__ th4,
    const unsigned* __restrict__ d2mb, float* __restrict__ srow,
    unsigned* __restrict__ jminrow, unsigned* __restrict__ negrow) {
    __shared__ __align__(16) char smem[32768];   // 2 bufs x (A 8K + B 8K)

    const int tid  = threadIdx.x;
    const int lane = tid & 63;
    const int w    = tid >> 6;        // 0..3
    const int wr   = w >> 1;          // 0..1 (M 64-half)
    const int wc   = w & 1;           // 0..1 (N 64-half)

    // XCD-aware bijective swizzle: 2080 = 8 XCDs x 260; triangle decode (64 rows)
    const int bid = (int)blockIdx.x;
    const int swz = (bid & 7) * 260 + (bid >> 3);
    int rb = (int)((129.0f - sqrtf(16641.0f - 8.0f * (float)swz)) * 0.5f);
    rb = rb < 0 ? 0 : (rb > 63 ? 63 : rb);
    while (tri_cum(rb + 1) <= swz) rb++;
    while (tri_cum(rb) > swz) rb--;
    const int cb = rb + (swz - tri_cum(rb));
    const bool isdiag = (rb == cb);
    const int r0 = rb * 128, c0 = cb * 128;

    // staging (BK=32): per buf, A = 128 rows x 64 B at [0], B at [8192].
    // thread t pass p: row = (t>>2) + 64p, slot = t&3; LDS dest linear t*16
    // (+4096/pass). global slot pre-swizzled: LDS[row][s] = g(row, s^((row>>1)&3)).
    const int ssw = (((tid & 3) ^ ((tid >> 3) & 3)) << 3);   // element offset
    const unsigned short* pA0 = e + (size_t)(r0 + (tid >> 2)) * D + ssw;
    const unsigned short* pA1 = pA0 + (size_t)64 * D;
    const unsigned short* pB0 = e + (size_t)(c0 + (tid >> 2)) * D + ssw;
    const unsigned short* pB1 = pB0 + (size_t)64 * D;

    const int fr = lane & 15;
    const int fq = lane >> 4;
    const int kslot = (fq ^ ((fr >> 1) & 3)) << 4;   // swizzled 16B slot (const/lane)

    f32x4 acc[4][4];
#pragma unroll
    for (int mt = 0; mt < 4; mt++)
#pragma unroll
        for (int nt = 0; nt < 4; nt++) acc[mt][nt] = (f32x4){0.f, 0.f, 0.f, 0.f};

#define STAGE(T, BUF) { \
    const int k0_ = (T) * 32; char* d_ = smem + (BUF) * 16384;   \
    gl_lds16(pA0 + k0_, d_ + tid * 16);                          \
    gl_lds16(pA1 + k0_, d_ + 4096 + tid * 16);                   \
    gl_lds16(pB0 + k0_, d_ + 8192 + tid * 16);                   \
    gl_lds16(pB1 + k0_, d_ + 12288 + tid * 16); }

#define COMPUTE(BUF) { \
    const char* cA_ = smem + (BUF) * 16384;                      \
    const char* cB_ = cA_ + 8192;                                \
    short8 a_[4], b_[4];                                         \
    _Pragma("unroll")                                            \
    for (int mt = 0; mt < 4; mt++)                               \
        a_[mt] = *(const short8*)(cA_ + (wr * 64 + mt * 16 + fr) * 64 + kslot); \
    _Pragma("unroll")                                            \
    for (int nt = 0; nt < 4; nt++)                               \
        b_[nt] = *(const short8*)(cB_ + (wc * 64 + nt * 16 + fr) * 64 + kslot); \
    _Pragma("unroll")                                            \
    for (int mt = 0; mt < 4; mt++)                               \
    _Pragma("unroll")                                            \
    for (int nt = 0; nt < 4; nt++)                               \
        acc[mt][nt] = __builtin_amdgcn_mfma_f32_16x16x32_bf16(   \
            a_[mt], b_[nt], acc[mt][nt], 0, 0, 0); }

#define KST(T)                                                    \
    if ((T) + 1 < 16) STAGE((T) + 1, ((T) + 1) & 1)               \
    COMPUTE((T) & 1)                                              \
    asm volatile("s_waitcnt vmcnt(0)" ::: "memory");              \
    __builtin_amdgcn_s_barrier();                                 \
    __builtin_amdgcn_sched_barrier(0);

    STAGE(0, 0)
    asm volatile("s_waitcnt vmcnt(0)" ::: "memory");
    __builtin_amdgcn_s_barrier();
    __builtin_amdgcn_sched_barrier(0);
    KST(0)  KST(1)  KST(2)  KST(3)
    KST(4)  KST(5)  KST(6)  KST(7)
    KST(8)  KST(9)  KST(10) KST(11)
    KST(12) KST(13) KST(14) KST(15)
#undef KST
#undef COMPUTE
#undef STAGE
    __syncthreads();   // LDS reused by the reduction below

    // ---- fused epilogue (acc is the exp2 argument directly) ----
    const float dmax = sqrtf(__uint_as_float(*d2mb)) + 1e-8f;
    const float p2 = 0.0225f * dmax * dmax;   // (0.15*dmax)^2
    const float n2 = 0.1225f * dmax * dmax;   // (0.35*dmax)^2

    const int j0 = c0 + wc * 64 + fr;
    float4 thj[4];
#pragma unroll
    for (int nt = 0; nt < 4; nt++) thj[nt] = th4[j0 + nt * 16];

    float*    lds_rs = (float*)smem;              // [2][128] row sums (by wc)
    unsigned* lds_rj = (unsigned*)(smem + 1024);
    unsigned* lds_rn = (unsigned*)(smem + 2048);
    float*    lds_cs = (float*)(smem + 3072);     // [2][128] col sums (by wr)
    unsigned* lds_cj = (unsigned*)(smem + 4096);
    unsigned* lds_cn = (unsigned*)(smem + 5120);

    float    csum[4]; unsigned cjm[4], cng[4];
#pragma unroll
    for (int nt = 0; nt < 4; nt++) { csum[nt] = 0.0f; cjm[nt] = 0xFFFFFFFFu; cng[nt] = 0u; }

    const int i0 = r0 + wr * 64 + fq * 4;
#pragma unroll
    for (int mt = 0; mt < 4; mt++) {
#pragma unroll
        for (int rr = 0; rr < 4; rr++) {
            const int i = i0 + mt * 16 + rr;
            const float4 ti = th4[i];
            float sv = 0.0f; unsigned jv = 0xFFFFFFFFu, nv = 0u;
#pragma unroll
            for (int nt = 0; nt < 4; nt++) {
                const int j = j0 + nt * 16;
                const float4 tj = thj[nt];
                float dot = ti.x * tj.x + ti.y * tj.y + ti.z * tj.z;
                float d2 = fmaf(-2.0f, dot, ti.w + tj.w);
                bool pos = isdiag ? ((d2 < p2) && (j != i)) : (d2 < p2);
                bool neg = (d2 > n2);
                float c = (pos || neg) ? exp2f(acc[mt][nt][rr]) : 0.0f;
                sv += c;
                if (neg) nv = 1u;
                if (pos) jv = min(jv, (unsigned)j);
                if (!isdiag) {
                    csum[nt] += c;
                    if (neg) cng[nt] = 1u;
                    if (pos) cjm[nt] = min(cjm[nt], (unsigned)i);
                }
            }
            // row-side reduce across the 16 fr-lanes
#pragma unroll
            for (int off = 1; off < 16; off <<= 1) {
                sv += __shfl_xor(sv, off, 64);
                jv = min(jv, (unsigned)__shfl_xor((int)jv, off, 64));
                nv |= (unsigned)__shfl_xor((int)nv, off, 64);
            }
            if (fr == 0) {
                const int rl = wr * 64 + mt * 16 + fq * 4 + rr;
                lds_rs[wc * 128 + rl] = sv;
                lds_rj[wc * 128 + rl] = jv;
                lds_rn[wc * 128 + rl] = nv;
            }
        }
    }

    // column-side reduce across the 4 fq groups (lane^16, lane^32)
    if (!isdiag) {
#pragma unroll
        for (int nt = 0; nt < 4; nt++) {
            float sv = csum[nt]; unsigned jv = cjm[nt], nv = cng[nt];
#pragma unroll
            for (int off = 16; off < 64; off <<= 1) {
                sv += __shfl_xor(sv, off, 64);
                jv = min(jv, (unsigned)__shfl_xor((int)jv, off, 64));
                nv |= (unsigned)__shfl_xor((int)nv, off, 64);
            }
            if (fq == 0) {
                const int cl = wc * 64 + nt * 16 + fr;
                lds_cs[wr * 128 + cl] = sv;
                lds_cj[wr * 128 + cl] = jv;
                lds_cn[wr * 128 + cl] = nv;
            }
        }
    }
    __syncthreads();
    if (tid < 128) {
        float    sv = lds_rs[tid] + lds_rs[128 + tid];
        unsigned jv = min(lds_rj[tid], lds_rj[128 + tid]);
        unsigned nv = lds_rn[tid] | lds_rn[128 + tid];
        atomicAdd(&srow[r0 + tid], sv);
        atomicMin(&jminrow[r0 + tid], jv);
        atomicOr(&negrow[r0 + tid], nv);
        if (!isdiag) {
            float    cv = lds_cs[tid] + lds_cs[128 + tid];
            unsigned cj = min(lds_cj[tid], lds_cj[128 + tid]);
            unsigned cn = lds_cn[tid] | lds_cn[128 + tid];
            atomicAdd(&srow[c0 + tid], cv);
            atomicMin(&jminrow[c0 + tid], cj);
            atomicOr(&negrow[c0 + tid], cn);
        }
    }
}

// K5: per-row finalize. e is pre-scaled: sim = dot_scaled * ln2.
__global__ void krow(const unsigned short* __restrict__ e, const float* __restrict__ srow,
                     const unsigned* __restrict__ jminrow, const unsigned* __restrict__ negrow,
                     float* __restrict__ pr, float* __restrict__ vf) {
    int row  = blockIdx.x * 4 + (threadIdx.x >> 6);
    int lane = threadIdx.x & 63;
    unsigned jmv = jminrow[row];
    bool valid = (jmv != 0xFFFFFFFFu) && (negrow[row] != 0u);
    float p = 0.0f;
    if (valid) {
        const uint4* a = (const uint4*)(e + (size_t)row * D);
        const uint4* b = (const uint4*)(e + (size_t)jmv * D);
        uint4 va = a[lane], vb = b[lane];
        float dot = 0.0f;
        dot += bf2f(va.x & 0xFFFFu) * bf2f(vb.x & 0xFFFFu);
        dot += bf2f(va.x >> 16)     * bf2f(vb.x >> 16);
        dot += bf2f(va.y & 0xFFFFu) * bf2f(vb.y & 0xFFFFu);
        dot += bf2f(va.y >> 16)     * bf2f(vb.y >> 16);
        dot += bf2f(va.z & 0xFFFFu) * bf2f(vb.z & 0xFFFFu);
        dot += bf2f(va.z >> 16)     * bf2f(vb.z >> 16);
        dot += bf2f(va.w & 0xFFFFu) * bf2f(vb.w & 0xFFFFu);
        dot += bf2f(va.w >> 16)     * bf2f(vb.w >> 16);
#pragma unroll
        for (int off = 1; off < 64; off <<= 1) dot += __shfl_xor(dot, off, 64);
        p = logf(srow[row]) - dot * 0.69314718f;
    }
    if (lane == 0) { pr[row] = p; vf[row] = valid ? 1.0f : 0.0f; }
}

// K6: deterministic fixed-tree reduction -> scalar loss.
__global__ void kfinal(const float* __restrict__ pr, const float* __restrict__ vf,
                       float* __restrict__ out) {
    __shared__ float ls[1024];
    __shared__ float lc[1024];
    int t = threadIdx.x;
    float sv = 0.0f, cv = 0.0f;
#pragma unroll
    for (int k = 0; k < 8; k++) { sv += pr[t * 8 + k]; cv += vf[t * 8 + k]; }
    ls[t] = sv; lc[t] = cv;
    __syncthreads();
    for (int off = 512; off > 0; off >>= 1) {
        if (t < off) { ls[t] += ls[t + off]; lc[t] += lc[t + off]; }
        __syncthreads();
    }
    if (t == 0) out[0] = (lc[0] > 0.0f) ? (ls[0] / lc[0]) : 0.0f;
}

extern "C" void kernel_launch(void* const* d_in, const int* in_sizes, int n_in,
                              void* d_out, int out_size, void* d_ws, size_t ws_size,
                              hipStream_t stream) {
    const float* emb = (const float*)d_in[0];
    const float* th  = (const float*)d_in[1];
    float* out = (float*)d_out;
    char* ws = (char*)d_ws;

    unsigned short* e    = (unsigned short*)(ws);
    float4*   th4        = (float4*)(ws + 8388608);
    float*    srow       = (float*)(ws + 8519680);
    unsigned* jminr      = (unsigned*)(ws + 8552448);
    unsigned* negr       = (unsigned*)(ws + 8585216);
    float*    pr         = (float*)(ws + 8617984);
    float*    vf         = (float*)(ws + 8650752);
    unsigned* d2mb       = (unsigned*)(ws + 8683520);

    kpack<<<32, 256, 0, stream>>>(th, th4, srow, jminr, negr, d2mb);
    knorm<<<N / 4, 256, 0, stream>>>(emb, e, th4, d2mb);
    kmain<<<2080, 256, 0, stream>>>(e, th4, d2mb, srow, jminr, negr);
    krow<<<N / 4, 256, 0, stream>>>(e, srow, jminr, negr, pr, vf);
    kfinal<<<1, 1024, 0, stream>>>(pr, vf, out);
}